// Round 8
// baseline (341.700 us; speedup 1.0000x reference)
//
#include <hip/hip_runtime.h>
#include <hip/hip_bf16.h>

typedef __bf16          bf16x8_t __attribute__((ext_vector_type(8)));
typedef float           f32x4_t  __attribute__((ext_vector_type(4)));

#define DIN      256
#define CONDN    128
#define BM       64
#define NTHREADS 256
#define NWAVE    4

// d_ws bf16 layout (element offsets): W^T, i.e. [N][K] row-major, K contiguous
#define OFF_WS1 0        // [512][128]
#define OFF_WS2 65536    // [512][512]
#define OFF_WS3 327680   // [128][512]
#define OFF_WT1 393216   // [512][128]
#define OFF_WT2 458752   // [512][512]
#define OFF_WT3 720896   // [128][512]
#define W_TOTAL 786432

__global__ void prep_w(const float* __restrict__ Ws1, const float* __restrict__ Ws2,
                       const float* __restrict__ Ws3, const float* __restrict__ Wt1,
                       const float* __restrict__ Wt2, const float* __restrict__ Wt3,
                       __hip_bfloat16* __restrict__ wt) {
  int idx = blockIdx.x * blockDim.x + threadIdx.x;
  if (idx >= W_TOTAL) return;
  const float* W; int K, N, off;
  if (idx < OFF_WS2)      { W = Ws1; K = 128; N = 512; off = idx - OFF_WS1; }
  else if (idx < OFF_WS3) { W = Ws2; K = 512; N = 512; off = idx - OFF_WS2; }
  else if (idx < OFF_WT1) { W = Ws3; K = 512; N = 128; off = idx - OFF_WS3; }
  else if (idx < OFF_WT2) { W = Wt1; K = 128; N = 512; off = idx - OFF_WT1; }
  else if (idx < OFF_WT3) { W = Wt2; K = 512; N = 512; off = idx - OFF_WT2; }
  else                    { W = Wt3; K = 512; N = 128; off = idx - OFF_WT3; }
  int n = off / K;
  int k = off - n * K;
  wt[idx] = __float2bfloat16(W[k * N + n]);   // transpose: WT[n][k] = W[k][n]
}

// Swizzled LDS element offset within a row: 8-elem (16 B) granules, g ^= (row&7).
#define SWZ(row, col) (((((col) >> 3) ^ ((row) & 7)) << 3) + ((col) & 7))

// acc += A[0:64][0:KTOT] * W^T[n-slice][0:KTOT]; A from swizzled LDS (stride 512),
// B direct from global (L2-resident). No per-step barrier: the whole layer is one
// stretch; compiler pipelines loads, twin co-resident block fills stalls.
template<int KTOT, int MTT, int NT>
__device__ __forceinline__ void mm_ldsA(const __hip_bfloat16* __restrict__ As,
                                        const __hip_bfloat16* __restrict__ Bsrc,
                                        const int l15, const int l4, f32x4_t acc[MTT][NT]) {
  const int xr = l15 & 7;
  const __hip_bfloat16* bp = Bsrc + (size_t)l15 * KTOT + l4 * 8;
  #pragma unroll 2
  for (int s = 0; s < KTOT / 32; ++s) {
    bf16x8_t b[NT], a[MTT];
    #pragma unroll
    for (int n = 0; n < NT; ++n)
      b[n] = *reinterpret_cast<const bf16x8_t*>(bp + (size_t)n * 16 * KTOT + s * 32);
    #pragma unroll
    for (int m = 0; m < MTT; ++m)
      a[m] = *reinterpret_cast<const bf16x8_t*>(
          &As[(m * 16 + l15) * 512 + (((s * 4 + l4) ^ xr) << 3)]);
    #pragma unroll
    for (int m = 0; m < MTT; ++m) {
      #pragma unroll
      for (int n = 0; n < NT; ++n)
        acc[m][n] = __builtin_amdgcn_mfma_f32_16x16x32_bf16(a[m], b[n], acc[m][n], 0, 0, 0);
    }
  }
}

// Layer 1: A built per-lane from global fp32 x (rows row0..row0+63, cols 0..127),
// converted to bf16 in regs. x tile is 64 KB fp32, L1/L2-cached (reused by s & t
// MLPs and the twin block). No LDS for A at all.
template<int NT>
__device__ __forceinline__ void mm_gA(const float* __restrict__ xbase,
                                      const __hip_bfloat16* __restrict__ Bsrc,
                                      const int l15, const int l4, f32x4_t acc[4][NT]) {
  const __hip_bfloat16* bp = Bsrc + (size_t)l15 * 128 + l4 * 8;
  #pragma unroll
  for (int s = 0; s < 4; ++s) {
    bf16x8_t b[NT], a[4];
    #pragma unroll
    for (int n = 0; n < NT; ++n)
      b[n] = *reinterpret_cast<const bf16x8_t*>(bp + (size_t)n * 16 * 128 + s * 32);
    #pragma unroll
    for (int m = 0; m < 4; ++m) {
      const float* xp = xbase + (size_t)(m * 16 + l15) * DIN + s * 32 + l4 * 8;
      const float4 v0 = *reinterpret_cast<const float4*>(xp);
      const float4 v1 = *reinterpret_cast<const float4*>(xp + 4);
      union { bf16x8_t v; __hip_bfloat16 b8[8]; } av;
      av.b8[0] = __float2bfloat16(v0.x); av.b8[1] = __float2bfloat16(v0.y);
      av.b8[2] = __float2bfloat16(v0.z); av.b8[3] = __float2bfloat16(v0.w);
      av.b8[4] = __float2bfloat16(v1.x); av.b8[5] = __float2bfloat16(v1.y);
      av.b8[6] = __float2bfloat16(v1.z); av.b8[7] = __float2bfloat16(v1.w);
      a[m] = av.v;
    }
    #pragma unroll
    for (int m = 0; m < 4; ++m) {
      #pragma unroll
      for (int n = 0; n < NT; ++n)
        acc[m][n] = __builtin_amdgcn_mfma_f32_16x16x32_bf16(a[m], b[n], acc[m][n], 0, 0, 0);
    }
  }
}

template<int MTT, int NT>
__device__ __forceinline__ void relu_store(f32x4_t acc[MTT][NT], const float* __restrict__ bias,
                                           const int n0, const int l15, const int l4,
                                           __hip_bfloat16* __restrict__ H) {
  #pragma unroll
  for (int n = 0; n < NT; ++n) {
    const int col = n0 + n * 16 + l15;
    const float bv = bias[col];
    #pragma unroll
    for (int m = 0; m < MTT; ++m) {
      #pragma unroll
      for (int r = 0; r < 4; ++r) {
        const int row = m * 16 + l4 * 4 + r;
        float v = fmaxf(acc[m][n][r] + bv, 0.0f);
        H[row * 512 + SWZ(row, col)] = __float2bfloat16(v);
      }
    }
  }
}

#define ZERO_ACC(acc, MTT, NT) do {                       \
    _Pragma("unroll") for (int m_ = 0; m_ < MTT; ++m_)    \
    _Pragma("unroll") for (int n_ = 0; n_ < NT; ++n_)     \
      acc[m_][n_] = (f32x4_t){0.f, 0.f, 0.f, 0.f};        \
  } while (0)

// 256-thr block, 64 KB LDS -> 2 blocks/CU (two independent barrier domains per
// CU; twin block's waves fill this block's latency/barrier bubbles).
// launch_bounds(256,2): 2 blocks -> 8 waves/CU -> 2 waves/SIMD -> 256-reg cap.
__global__ __launch_bounds__(NTHREADS, 2)
void realnvp_fused(const float* __restrict__ x, const __hip_bfloat16* __restrict__ wt,
                   const float* __restrict__ bs1, const float* __restrict__ bs2,
                   const float* __restrict__ bs3, const float* __restrict__ bt1,
                   const float* __restrict__ bt2, const float* __restrict__ bt3,
                   float* __restrict__ y, float* __restrict__ ld) {
  __shared__ __hip_bfloat16 sH[BM * 512];     // 64 KB, swizzled, reused 4x
  float* sLd = reinterpret_cast<float*>(sH);  // [4][64] overlay, used after final barrier

  const int tid  = threadIdx.x;
  const int lane = tid & 63;
  const int wid  = tid >> 6;        // 0..3
  const int l15  = lane & 15;
  const int l4   = lane >> 4;
  const int row0 = blockIdx.x * BM;
  const int n0   = wid * 128;       // layer 1/2 column slice (NT=8)
  const int n3   = wid * 32;        // layer 3 column slice (NT=2)
  const float* xbase = x + (size_t)row0 * DIN;

  // cond passthrough: y[:, :128] = x[:, :128] (exact fp32), pure global->global
  #pragma unroll
  for (int i = 0; i < 8; ++i) {
    int f = tid + i * NTHREADS;              // 2048 float4 chunks: 64 rows x 32
    int r = f >> 5;
    int c = (f & 31) << 2;
    const float4 v = *reinterpret_cast<const float4*>(&xbase[(size_t)r * DIN + c]);
    *reinterpret_cast<float4*>(&y[(size_t)(row0 + r) * DIN + c]) = v;
  }

  f32x4_t acc[4][8];
  f32x4_t sfrag[4][2], tfrag[4][2];

  // ===================== MLP s =====================
  ZERO_ACC(acc, 4, 8);
  mm_gA<8>(xbase, wt + OFF_WS1 + (size_t)n0 * 128, l15, l4, acc);
  relu_store<4, 8>(acc, bs1, n0, l15, l4, sH);
  __syncthreads();   // B1: sH = h1s
  ZERO_ACC(acc, 4, 8);
  mm_ldsA<512, 4, 8>(sH, wt + OFF_WS2 + (size_t)n0 * 512, l15, l4, acc);
  __syncthreads();   // B2: all h1s reads done
  relu_store<4, 8>(acc, bs2, n0, l15, l4, sH);
  __syncthreads();   // B3: sH = h2s
  {
    f32x4_t a3[4][2];
    ZERO_ACC(a3, 4, 2);
    mm_ldsA<512, 4, 2>(sH, wt + OFF_WS3 + (size_t)n3 * 512, l15, l4, a3);
    #pragma unroll
    for (int m = 0; m < 4; ++m) { sfrag[m][0] = a3[m][0]; sfrag[m][1] = a3[m][1]; }
  }

  // ===================== MLP t =====================
  // t-L1 touches no LDS -> issue its MFMAs before the barrier that gates h2s reuse
  ZERO_ACC(acc, 4, 8);
  mm_gA<8>(xbase, wt + OFF_WT1 + (size_t)n0 * 128, l15, l4, acc);
  __syncthreads();   // B4: all h2s reads (s-L3) done
  relu_store<4, 8>(acc, bt1, n0, l15, l4, sH);
  __syncthreads();   // B5: sH = h1t
  ZERO_ACC(acc, 4, 8);
  mm_ldsA<512, 4, 8>(sH, wt + OFF_WT2 + (size_t)n0 * 512, l15, l4, acc);
  __syncthreads();   // B6: all h1t reads done
  relu_store<4, 8>(acc, bt2, n0, l15, l4, sH);
  __syncthreads();   // B7: sH = h2t
  {
    f32x4_t a3[4][2];
    ZERO_ACC(a3, 4, 2);
    mm_ldsA<512, 4, 2>(sH, wt + OFF_WT3 + (size_t)n3 * 512, l15, l4, a3);
    #pragma unroll
    for (int m = 0; m < 4; ++m) { tfrag[m][0] = a3[m][0]; tfrag[m][1] = a3[m][1]; }
  }
  __syncthreads();   // B8: all h2t reads done; sLd overlay now safe

  // ===================== epilogue (wave owns 64 rows x 32 cols) =====================
  const float bs0 = bs3[n3 + l15];
  const float bs1v = bs3[n3 + 16 + l15];
  const float bt0 = bt3[n3 + l15];
  const float bt1v = bt3[n3 + 16 + l15];
  #pragma unroll
  for (int m = 0; m < 4; ++m) {
    #pragma unroll
    for (int r = 0; r < 4; ++r) {
      const int rl   = m * 16 + l4 * 4 + r;
      const int grow = row0 + rl;
      const int c0   = n3 + l15;
      const int c1   = n3 + 16 + l15;
      float s0 = tanhf(sfrag[m][0][r] + bs0);
      float s1 = tanhf(sfrag[m][1][r] + bs1v);
      float t0 = tfrag[m][0][r] + bt0;
      float t1 = tfrag[m][1][r] + bt1v;
      float xv0 = x[(size_t)grow * DIN + CONDN + c0];
      float xv1 = x[(size_t)grow * DIN + CONDN + c1];
      y[(size_t)grow * DIN + CONDN + c0] = xv0 * expf(s0) + t0;
      y[(size_t)grow * DIN + CONDN + c1] = xv1 * expf(s1) + t1;
      float ss = s0 + s1;
      ss += __shfl_xor(ss, 1);
      ss += __shfl_xor(ss, 2);
      ss += __shfl_xor(ss, 4);
      ss += __shfl_xor(ss, 8);
      if (l15 == 0) sLd[wid * BM + rl] = ss;
    }
  }
  __syncthreads();   // B9: partials ready
  if (tid < BM) {
    float v = 0.f;
    #pragma unroll
    for (int w = 0; w < NWAVE; ++w) v += sLd[w * BM + tid];
    ld[row0 + tid] = v;
  }
}

extern "C" void kernel_launch(void* const* d_in, const int* in_sizes, int n_in,
                              void* d_out, int out_size, void* d_ws, size_t ws_size,
                              hipStream_t stream) {
  const float* x   = (const float*)d_in[0];
  const float* Ws1 = (const float*)d_in[1];
  const float* bs1 = (const float*)d_in[2];
  const float* Ws2 = (const float*)d_in[3];
  const float* bs2 = (const float*)d_in[4];
  const float* Ws3 = (const float*)d_in[5];
  const float* bs3 = (const float*)d_in[6];
  const float* Wt1 = (const float*)d_in[7];
  const float* bt1 = (const float*)d_in[8];
  const float* Wt2 = (const float*)d_in[9];
  const float* bt2 = (const float*)d_in[10];
  const float* Wt3 = (const float*)d_in[11];
  const float* bt3 = (const float*)d_in[12];

  const int Btot = in_sizes[0] / DIN;          // 65536
  float* y  = (float*)d_out;
  float* ld = (float*)d_out + (size_t)Btot * DIN;
  __hip_bfloat16* wt = (__hip_bfloat16*)d_ws;  // 1.5 MB needed

  prep_w<<<(W_TOTAL + 255) / 256, 256, 0, stream>>>(Ws1, Ws2, Ws3, Wt1, Wt2, Wt3, wt);
  realnvp_fused<<<Btot / BM, NTHREADS, 0, stream>>>(x, wt, bs1, bs2, bs3,
                                                    bt1, bt2, bt3, y, ld);
}